// Round 1
// baseline (1012.033 us; speedup 1.0000x reference)
//
#include <hip/hip_runtime.h>

// Problem: B=8, C=64, T=2048, J=64, Ci=32, all fp32.
// out[b,o,t,j] = sum_c w_out[o,c]*y[b,t,j,c] + b_out[o] + x[b,o,t,j]
// y[b,t,j,o]   = (1/64) sum_i relu(a[j] + bb[j,i]) * g[i,o]
// with a/bb folded into weight-only precomputes WA = P1@w_theta, WB = P2@w_phi.

#define TT 2048
#define XCH (2048 * 64)       // c-stride in x: T*J = 131072
#define XB  (64 * 2048 * 64)  // b-stride in x: C*T*J = 8388608

// ws layout (floats): [0,4096) WA[j][c]; [4096,8192) WB[j][c]; [8192,8256) c_ab[j]
__global__ __launch_bounds__(256) void prep_kernel(
    const float* __restrict__ w_theta, const float* __restrict__ b_theta,
    const float* __restrict__ w_phi,   const float* __restrict__ b_phi,
    const float* __restrict__ proj,    float* __restrict__ ws)
{
    int e = blockIdx.x * 256 + threadIdx.x;   // 0..4095
    int j = e >> 6, cc = e & 63;
    const float* pj = proj + j * 64;          // proj row: (J, 2*Ci, 1) flat
    float sa = 0.f, sb = 0.f;
    #pragma unroll
    for (int o = 0; o < 32; ++o) {
        sa += pj[o]      * w_theta[o * 64 + cc];
        sb += pj[32 + o] * w_phi[o * 64 + cc];
    }
    ws[e]        = sa;   // WA
    ws[4096 + e] = sb;   // WB
    if (e < 64) {
        float s = 0.f;
        #pragma unroll
        for (int o = 0; o < 32; ++o)
            s += proj[e * 64 + o] * b_theta[o] + proj[e * 64 + 32 + o] * b_phi[o];
        ws[8192 + e] = s;  // ca[j] + cb[j]
    }
}

// One workgroup per (b,t). 256 threads = 4 waves.
__global__ __launch_bounds__(256, 2) void tnl_main(
    const float* __restrict__ x,
    const float* __restrict__ w_g,   const float* __restrict__ b_g,
    const float* __restrict__ w_out, const float* __restrict__ b_out,
    const float* __restrict__ ws,
    float* __restrict__ out)
{
    // LDS: 16K + 17K + 8.5K + 16K + 8.25K + 256B = 66 KB -> 2 blocks/CU
    __shared__ __align__(16) float Xs[64][64];    // [c][j] : residual + a-step
    __shared__ __align__(16) float XsT[64][68];   // [j][c] : stride 68 => conflict-free b128 rows
    __shared__ __align__(16) float GsT[32][68];   // [o][i] : g transposed, i contiguous
    __shared__ __align__(16) float Fs[64][64];    // [j][i] : relu(a+bb)
    __shared__ __align__(16) float Ys[64][33];    // [j][o] : +1 pad for column reads
    __shared__ float Afull[64];

    const int tid  = threadIdx.x;
    const int lane = tid & 63;
    const int wv   = __builtin_amdgcn_readfirstlane(tid >> 6); // wave id 0..3 (scalar)

    const int bt = blockIdx.x;
    const int b  = bt >> 11;          // T = 2048
    const int t  = bt & (TT - 1);
    const float* xb = x   + (size_t)b * XB + (size_t)t * 64;
    float*       ob = out + (size_t)b * XB + (size_t)t * 64;

    // ---- Step 1: load x[b,:,t,:] (64x64), store straight + transposed ----
    {
        int j4 = (tid & 15) * 4;
        int c0 = tid >> 4;            // 0..15
        #pragma unroll
        for (int r = 0; r < 4; ++r) {
            int c = c0 + r * 16;
            float4 v = *(const float4*)(xb + (size_t)c * XCH + j4);
            *(float4*)&Xs[c][j4] = v;
            XsT[j4 + 0][c] = v.x;
            XsT[j4 + 1][c] = v.y;
            XsT[j4 + 2][c] = v.z;
            XsT[j4 + 3][c] = v.w;
        }
    }
    __syncthreads();

    // ---- Step 2: GsT[o][i] = w_g[o]·x[:,i] + b_g[o] ; lane = i, wave owns 8 o's ----
    {
        const float4* xr = (const float4*)&XsT[lane][0];
        float acc[8] = {0, 0, 0, 0, 0, 0, 0, 0};
        #pragma unroll 4
        for (int c4 = 0; c4 < 16; ++c4) {
            float4 xv = xr[c4];
            #pragma unroll
            for (int oo = 0; oo < 8; ++oo) {
                int o = wv * 8 + oo;  // wave-uniform -> s_load
                float4 w4 = *(const float4*)(w_g + o * 64 + c4 * 4);
                acc[oo] += w4.x * xv.x + w4.y * xv.y + w4.z * xv.z + w4.w * xv.w;
            }
        }
        #pragma unroll
        for (int oo = 0; oo < 8; ++oo) {
            int o = wv * 8 + oo;
            GsT[o][lane] = acc[oo] + b_g[o];
        }
    }
    // a[j] = WA[j]·x[:,j] + c_ab[j] (wave 0, lane = j)
    if (wv == 0) {
        const float4* xr = (const float4*)&XsT[lane][0];
        float s = 0.f;
        #pragma unroll 4
        for (int c4 = 0; c4 < 16; ++c4) {
            float4 xv = xr[c4];
            float4 w4 = *(const float4*)(ws + lane * 64 + c4 * 4);
            s += w4.x * xv.x + w4.y * xv.y + w4.z * xv.z + w4.w * xv.w;
        }
        Afull[lane] = s + ws[8192 + lane];
    }
    __syncthreads();

    // ---- Step 3: Fs[j][i] = relu(a[j] + WB[j]·x[:,i]) ; lane = i, wave owns 16 j's ----
    {
        const float* WB = ws + 4096;
        const float4* xr = (const float4*)&XsT[lane][0];
        float acc[16];
        #pragma unroll
        for (int jj = 0; jj < 16; ++jj) acc[jj] = 0.f;
        #pragma unroll 2
        for (int c4 = 0; c4 < 16; ++c4) {
            float4 xv = xr[c4];
            #pragma unroll
            for (int jj = 0; jj < 16; ++jj) {
                int j = wv * 16 + jj;  // wave-uniform -> s_load
                float4 w4 = *(const float4*)(WB + j * 64 + c4 * 4);
                acc[jj] += w4.x * xv.x + w4.y * xv.y + w4.z * xv.z + w4.w * xv.w;
            }
        }
        #pragma unroll
        for (int jj = 0; jj < 16; ++jj) {
            int j = wv * 16 + jj;
            float v = acc[jj] + Afull[j];
            Fs[j][lane] = v > 0.f ? v : 0.f;
        }
    }
    __syncthreads();

    // ---- Step 4: Ys[j][o] = (1/64) sum_i Fs[j][i] * GsT[o][i] ----
    // lane: o = lane&31, h = lane>>5 splits K; wave owns 16 j's; shfl-reduce halves.
    {
        const int o = lane & 31;
        const int h = lane >> 5;
        float4 gr[8];
        const float4* gp = (const float4*)&GsT[o][h * 32];
        #pragma unroll
        for (int q = 0; q < 8; ++q) gr[q] = gp[q];
        #pragma unroll
        for (int jj = 0; jj < 16; ++jj) {
            int j = wv * 16 + jj;
            const float4* fr = (const float4*)&Fs[j][h * 32];
            float s = 0.f;
            #pragma unroll
            for (int q = 0; q < 8; ++q) {
                float4 fv = fr[q];
                s += fv.x * gr[q].x + fv.y * gr[q].y + fv.z * gr[q].z + fv.w * gr[q].w;
            }
            s += __shfl_xor(s, 32, 64);
            if (h == 0) Ys[j][o] = s * (1.0f / 64.0f);
        }
    }
    __syncthreads();

    // ---- Step 5: out[o2][j] = w_out[o2]·Ys[j] + b_out[o2] + Xs[o2][j] ; lane = j ----
    {
        float acc[16];
        #pragma unroll
        for (int k = 0; k < 16; ++k) acc[k] = b_out[wv * 16 + k];
        #pragma unroll 2
        for (int o4 = 0; o4 < 8; ++o4) {
            float y0 = Ys[lane][o4 * 4 + 0];
            float y1 = Ys[lane][o4 * 4 + 1];
            float y2 = Ys[lane][o4 * 4 + 2];
            float y3 = Ys[lane][o4 * 4 + 3];
            #pragma unroll
            for (int k = 0; k < 16; ++k) {
                int o2 = wv * 16 + k;  // wave-uniform -> s_load
                float4 w4 = *(const float4*)(w_out + o2 * 32 + o4 * 4);
                acc[k] += w4.x * y0 + w4.y * y1 + w4.z * y2 + w4.w * y3;
            }
        }
        #pragma unroll
        for (int k = 0; k < 16; ++k) {
            int o2 = wv * 16 + k;
            ob[(size_t)o2 * XCH + lane] = acc[k] + Xs[o2][lane];
        }
    }
}

extern "C" void kernel_launch(void* const* d_in, const int* in_sizes, int n_in,
                              void* d_out, int out_size, void* d_ws, size_t ws_size,
                              hipStream_t stream) {
    const float* x       = (const float*)d_in[0];
    const float* w_g     = (const float*)d_in[1];
    const float* b_g     = (const float*)d_in[2];
    const float* w_theta = (const float*)d_in[3];
    const float* b_theta = (const float*)d_in[4];
    const float* w_phi   = (const float*)d_in[5];
    const float* b_phi   = (const float*)d_in[6];
    const float* proj    = (const float*)d_in[7];
    const float* w_out   = (const float*)d_in[8];
    const float* b_out   = (const float*)d_in[9];
    float* out = (float*)d_out;
    float* ws  = (float*)d_ws;   // needs 8256 floats = 33 KB

    prep_kernel<<<16, 256, 0, stream>>>(w_theta, b_theta, w_phi, b_phi, proj, ws);
    tnl_main<<<8 * 2048, 256, 0, stream>>>(x, w_g, b_g, w_out, b_out, ws, out);
}

// Round 2
// 537.243 us; speedup vs baseline: 1.8838x; 1.8838x over previous
//
#include <hip/hip_runtime.h>

// B=8, C=64, T=2048, J=64, Ci=32, fp32 in/out. bf16 MFMA internally.
// out[b,o2,t,j] = sum_o w_out[o2,o]*Y[j,o] + b_out[o2] + x[b,o2,t,j]
// Y[j,o] = sum_i relu(a[j]+BB[j,i]) * (g[i,o]/64);  BB = WB@x, G = (Wg/64)@x + b_g/64
// a[j] = WA[j]@x[:,j] + cab[j];  WA = P1@w_theta, WB = P2@w_phi (prep kernel).

#define TT 2048
#define XCH (2048 * 64)       // c-stride in x
#define XB  (64 * 2048 * 64)  // b-stride in x

typedef __attribute__((ext_vector_type(8))) short bshort8;
typedef __attribute__((ext_vector_type(4))) float f32x4;

__device__ inline unsigned short f2bf(float f) {
    unsigned u = __builtin_bit_cast(unsigned, f);
    u += 0x7FFFu + ((u >> 16) & 1u);     // RNE
    return (unsigned short)(u >> 16);
}
__device__ inline float bf2f(unsigned short h) {
    unsigned u = ((unsigned)h) << 16;
    return __builtin_bit_cast(float, u);
}

// ws layout (shorts): [0,4096) WAb[j][c]; [4096,8192) WBb[j][c];
// [8192,10240) Wgb[o][c] (scaled 1/64); [10240,12288) Woutb[o2][o];
// then floats at short-offset 12288: cab[64], bgs[32] (= b_g/64).
__global__ __launch_bounds__(256) void prep_kernel(
    const float* __restrict__ w_theta, const float* __restrict__ b_theta,
    const float* __restrict__ w_phi,   const float* __restrict__ b_phi,
    const float* __restrict__ proj,    const float* __restrict__ w_g,
    const float* __restrict__ b_g,     const float* __restrict__ w_out,
    unsigned short* __restrict__ ws16)
{
    int e = blockIdx.x * 256 + threadIdx.x;   // 0..4095
    int j = e >> 6, cc = e & 63;
    const float* pj = proj + j * 64;
    float sa = 0.f, sb = 0.f;
    #pragma unroll
    for (int o = 0; o < 32; ++o) {
        sa += pj[o]      * w_theta[o * 64 + cc];
        sb += pj[32 + o] * w_phi[o * 64 + cc];
    }
    ws16[e]        = f2bf(sa);                       // WAb
    ws16[4096 + e] = f2bf(sb);                       // WBb
    if (e < 2048) ws16[8192 + e]  = f2bf(w_g[e] * (1.0f / 64.0f));   // Wgb
    if (e < 2048) ws16[10240 + e] = f2bf(w_out[e]);                  // Woutb
    float* wf = (float*)(ws16 + 12288);
    if (e < 64) {
        float s = 0.f;
        #pragma unroll
        for (int o = 0; o < 32; ++o)
            s += proj[e * 64 + o] * b_theta[o] + proj[e * 64 + 32 + o] * b_phi[o];
        wf[e] = s;                                   // cab[j]
    }
    if (e < 32) wf[64 + e] = b_g[e] * (1.0f / 64.0f); // bgs
}

#define STRA 80   // XsT/Fs row stride (shorts): 160B rows -> every b128 16B-aligned
#define STRG 80   // GsT row stride
#define STRY 40   // Ys row stride (80B rows, 16B-aligned at 8q offsets)

// One wave (64 threads) per (b,t) tile. No __syncthreads needed after const stage.
__global__ __launch_bounds__(64, 2) void tnl_mfma(
    const float* __restrict__ x,
    const unsigned short* __restrict__ ws16,
    const float* __restrict__ b_out,
    float* __restrict__ out)
{
    __shared__ short regA[64 * STRA];   // XsT bf16 -> reused as Fs
    __shared__ short regB[64 * STRY];   // GsT (32*80=2560) -> reused as Ys (64*40=2560)
    __shared__ float Af[64];            // a[j]
    __shared__ float cons[160];         // [0,32) bgs  [32,96) cab  [96,160) b_out

    const int lane = threadIdx.x;       // 0..63
    const int l15  = lane & 15;
    const int q    = lane >> 4;

    const unsigned short* wab = ws16;
    const unsigned short* wbb = ws16 + 4096;
    const unsigned short* wgb = ws16 + 8192;
    const unsigned short* wob = ws16 + 10240;
    const float* wf = (const float*)(ws16 + 12288);

    // const staging (single wave: lgkmcnt ordering suffices, no barrier)
    if (lane < 32) cons[lane] = wf[64 + lane];   // bgs
    cons[32 + lane] = wf[lane];                  // cab
    cons[96 + lane] = b_out[lane];

    const int bt = blockIdx.x;
    const int b  = bt >> 11;
    const int t  = bt & (TT - 1);
    const float* xb = x + (size_t)b * XB + (size_t)t * 64;

    // ---- stage x[b,:,t,:] -> XsT[j][c] bf16 (lane = j) ----
    {
        const float* xp = xb + lane;
        #pragma unroll
        for (int c0 = 0; c0 < 64; c0 += 4) {
            float f0 = xp[(size_t)(c0 + 0) * XCH];
            float f1 = xp[(size_t)(c0 + 1) * XCH];
            float f2 = xp[(size_t)(c0 + 2) * XCH];
            float f3 = xp[(size_t)(c0 + 3) * XCH];
            unsigned long long pk =
                (unsigned long long)f2bf(f0) |
                ((unsigned long long)f2bf(f1) << 16) |
                ((unsigned long long)f2bf(f2) << 32) |
                ((unsigned long long)f2bf(f3) << 48);
            *(unsigned long long*)(&regA[lane * STRA + c0]) = pk;
        }
    }

    // ---- a[j] = WA[j]·x[:,j] + cab[j]  (lane = j, reads own row) ----
    {
        float s = cons[32 + lane];
        #pragma unroll
        for (int k0 = 0; k0 < 64; k0 += 8) {
            bshort8 xv = *(const bshort8*)(&regA[lane * STRA + k0]);
            bshort8 wv = *(const bshort8*)(wab + lane * 64 + k0);
            #pragma unroll
            for (int e = 0; e < 8; ++e)
                s += bf2f((unsigned short)xv[e]) * bf2f((unsigned short)wv[e]);
        }
        Af[lane] = s;
    }

    // ---- weight fragments (held in VGPRs) ----
    bshort8 wbA[4][2];   // WB as A-operand: m=j, k=c
    #pragma unroll
    for (int mt = 0; mt < 4; ++mt)
        #pragma unroll
        for (int kt = 0; kt < 2; ++kt)
            wbA[mt][kt] = *(const bshort8*)(wbb + (16 * mt + l15) * 64 + 32 * kt + 8 * q);
    bshort8 wgA[2][2];   // Wg as A-operand: m=o, k=c
    #pragma unroll
    for (int m2 = 0; m2 < 2; ++m2)
        #pragma unroll
        for (int kt = 0; kt < 2; ++kt)
            wgA[m2][kt] = *(const bshort8*)(wgb + (16 * m2 + l15) * 64 + 32 * kt + 8 * q);

    // ---- x fragments: A[i][c] == B[c][i] (same lane mapping) ----
    bshort8 xf[4][2];
    #pragma unroll
    for (int it = 0; it < 4; ++it)
        #pragma unroll
        for (int kt = 0; kt < 2; ++kt)
            xf[it][kt] = *(const bshort8*)(&regA[(16 * it + l15) * STRA + 32 * kt + 8 * q]);

    // ---- M2: BB = WB @ x  (M=j 64, N=i 64, K=c 64) ----
    f32x4 bb[4][4];
    #pragma unroll
    for (int mt = 0; mt < 4; ++mt)
        #pragma unroll
        for (int nt = 0; nt < 4; ++nt) {
            f32x4 c = {0.f, 0.f, 0.f, 0.f};
            c = __builtin_amdgcn_mfma_f32_16x16x32_bf16(wbA[mt][0], xf[nt][0], c, 0, 0, 0);
            c = __builtin_amdgcn_mfma_f32_16x16x32_bf16(wbA[mt][1], xf[nt][1], c, 0, 0, 0);
            bb[mt][nt] = c;
        }

    // ---- relu(a + bb) -> Fs[j][i] bf16 (overwrites XsT; xf already in regs) ----
    {
        float av[4][4];
        #pragma unroll
        for (int mt = 0; mt < 4; ++mt)
            #pragma unroll
            for (int r = 0; r < 4; ++r)
                av[mt][r] = Af[16 * mt + 4 * q + r];
        #pragma unroll
        for (int mt = 0; mt < 4; ++mt)
            #pragma unroll
            for (int nt = 0; nt < 4; ++nt)
                #pragma unroll
                for (int r = 0; r < 4; ++r) {
                    float v = bb[mt][nt][r] + av[mt][r];
                    v = v > 0.f ? v : 0.f;
                    regA[(16 * mt + 4 * q + r) * STRA + 16 * nt + l15] = (short)f2bf(v);
                }
    }

    // ---- M1: Gt = (Wg/64) @ x  (M=o 32, N=i 64, K=c 64) ----
    f32x4 gt[2][4];
    #pragma unroll
    for (int m2 = 0; m2 < 2; ++m2)
        #pragma unroll
        for (int nt = 0; nt < 4; ++nt) {
            f32x4 c = {0.f, 0.f, 0.f, 0.f};
            c = __builtin_amdgcn_mfma_f32_16x16x32_bf16(wgA[m2][0], xf[nt][0], c, 0, 0, 0);
            c = __builtin_amdgcn_mfma_f32_16x16x32_bf16(wgA[m2][1], xf[nt][1], c, 0, 0, 0);
            gt[m2][nt] = c;
        }

    // ---- Gt + bgs -> GsT[o][i] bf16 in regB ----
    {
        float bgv[2][4];
        #pragma unroll
        for (int m2 = 0; m2 < 2; ++m2)
            #pragma unroll
            for (int r = 0; r < 4; ++r)
                bgv[m2][r] = cons[16 * m2 + 4 * q + r];
        #pragma unroll
        for (int m2 = 0; m2 < 2; ++m2)
            #pragma unroll
            for (int nt = 0; nt < 4; ++nt)
                #pragma unroll
                for (int r = 0; r < 4; ++r) {
                    float v = gt[m2][nt][r] + bgv[m2][r];
                    regB[(16 * m2 + 4 * q + r) * STRG + 16 * nt + l15] = (short)f2bf(v);
                }
    }

    // ---- M3: Y = F @ G  (M=j 64, N=o 32, K=i 64) ----
    f32x4 yy[4][2];
    {
        bshort8 fA[4][2];
        #pragma unroll
        for (int mt = 0; mt < 4; ++mt)
            #pragma unroll
            for (int kt = 0; kt < 2; ++kt)
                fA[mt][kt] = *(const bshort8*)(&regA[(16 * mt + l15) * STRA + 32 * kt + 8 * q]);
        bshort8 gB[2][2];   // B[k=i][n=o] read from GsT[o][i]
        #pragma unroll
        for (int kt = 0; kt < 2; ++kt)
            #pragma unroll
            for (int n2 = 0; n2 < 2; ++n2)
                gB[kt][n2] = *(const bshort8*)(&regB[(16 * n2 + l15) * STRG + 32 * kt + 8 * q]);
        #pragma unroll
        for (int mt = 0; mt < 4; ++mt)
            #pragma unroll
            for (int n2 = 0; n2 < 2; ++n2) {
                f32x4 c = {0.f, 0.f, 0.f, 0.f};
                c = __builtin_amdgcn_mfma_f32_16x16x32_bf16(fA[mt][0], gB[0][n2], c, 0, 0, 0);
                c = __builtin_amdgcn_mfma_f32_16x16x32_bf16(fA[mt][1], gB[1][n2], c, 0, 0, 0);
                yy[mt][n2] = c;
            }
    }

    // ---- Y -> Ys[j][o] bf16 (overwrites GsT; gB already consumed) ----
    #pragma unroll
    for (int mt = 0; mt < 4; ++mt)
        #pragma unroll
        for (int n2 = 0; n2 < 2; ++n2)
            #pragma unroll
            for (int r = 0; r < 4; ++r)
                regB[(16 * mt + 4 * q + r) * STRY + 16 * n2 + l15] = (short)f2bf(yy[mt][n2][r]);

    // ---- M4: Out = Wout @ Y^T  (M=o2 64, N=j 64, K=o 32) + epilogue ----
    {
        bshort8 woA[4];
        #pragma unroll
        for (int mt = 0; mt < 4; ++mt)
            woA[mt] = *(const bshort8*)(wob + (16 * mt + l15) * 32 + 8 * q);
        bshort8 yB[4];   // B[k=o][n=j] from Ys[j][o]
        #pragma unroll
        for (int nt = 0; nt < 4; ++nt)
            yB[nt] = *(const bshort8*)(&regB[(16 * nt + l15) * STRY + 8 * q]);

        float bov[4][4];
        #pragma unroll
        for (int mt = 0; mt < 4; ++mt)
            #pragma unroll
            for (int r = 0; r < 4; ++r)
                bov[mt][r] = cons[96 + 16 * mt + 4 * q + r];

        float* ob = out + (size_t)b * XB + (size_t)t * 64;
        #pragma unroll
        for (int mt = 0; mt < 4; ++mt)
            #pragma unroll
            for (int nt = 0; nt < 4; ++nt) {
                f32x4 c = {0.f, 0.f, 0.f, 0.f};
                c = __builtin_amdgcn_mfma_f32_16x16x32_bf16(woA[mt], yB[nt], c, 0, 0, 0);
                #pragma unroll
                for (int r = 0; r < 4; ++r) {
                    int o2 = 16 * mt + 4 * q + r;
                    int j  = 16 * nt + l15;
                    size_t idx = (size_t)o2 * XCH + j;
                    ob[idx] = c[r] + bov[mt][r] + xb[idx];   // fp32 residual
                }
            }
    }
}

extern "C" void kernel_launch(void* const* d_in, const int* in_sizes, int n_in,
                              void* d_out, int out_size, void* d_ws, size_t ws_size,
                              hipStream_t stream) {
    const float* x       = (const float*)d_in[0];
    const float* w_g     = (const float*)d_in[1];
    const float* b_g     = (const float*)d_in[2];
    const float* w_theta = (const float*)d_in[3];
    const float* b_theta = (const float*)d_in[4];
    const float* w_phi   = (const float*)d_in[5];
    const float* b_phi   = (const float*)d_in[6];
    const float* proj    = (const float*)d_in[7];
    const float* w_out   = (const float*)d_in[8];
    const float* b_out   = (const float*)d_in[9];
    float* out = (float*)d_out;
    unsigned short* ws16 = (unsigned short*)d_ws;   // needs 24960 bytes

    prep_kernel<<<16, 256, 0, stream>>>(w_theta, b_theta, w_phi, b_phi, proj,
                                        w_g, b_g, w_out, ws16);
    tnl_mfma<<<8 * 2048, 64, 0, stream>>>(x, ws16, b_out, out);
}